// Round 9
// baseline (35.910 us; speedup 1.0000x reference)
//
#include <hip/hip_runtime.h>

// Loss = weighted-BCE(score)/m + Huber(geometry)/(8*n_pix), single fused pass.
// beta = 1 - sum(Y_true_score)/N factors out: S0=sum(yt), S1=sum(yt*log(yp)),
// S2=sum((1-yt)*log(1-yp)), SG=sum(huber); finalize combines.
//
// Round-9: load-balance experiment. R2..R8 established that wave-level MLP
// (2..18 loads in flight) does NOT move the reduce kernel (~50us profiled,
// ~5.1 TB/s effective mixed HBM+L3). Remaining hypotheses: (a) exact-fill
// grid (2048 blocks = device capacity) cannot rebalance across CUs when
// some waves hit HBM-miss-heavy lines (occupancy 43-70% swings support
// this); (b) mixed L3/HBM path wall. This round: 4608 blocks (2.25x
// oversubscribed) with role-split blocks — geometry-only [0,4096) doing one
// R2-proven 4-deep batch per thread, score-only [4096,4608) (log-heavy,
// 11% of traffic, dispatched last to fill the tail). Null result => (b)
// confirmed, declare roofline.
// Reduction tail / finalize / generic fallback byte-identical to R2/R5
// (known-good; R4 proved fused atomic tails cost ~100us on this chip).

#define THREADS 256
#define GEO_BLOCKS 4096
#define SCORE_BLOCKS 512
#define TOTAL_BLOCKS (GEO_BLOCKS + SCORE_BLOCKS)
#define FALLBACK_BLOCKS 2048

__device__ __forceinline__ float huber4f(float4 t, float4 p) {
    float dx = fabsf(t.x - p.x);
    float dy = fabsf(t.y - p.y);
    float dz = fabsf(t.z - p.z);
    float dw = fabsf(t.w - p.w);
    float hx = (dx < 1.f) ? 0.5f * dx * dx : dx - 0.5f;
    float hy = (dy < 1.f) ? 0.5f * dy * dy : dy - 0.5f;
    float hz = (dz < 1.f) ? 0.5f * dz * dz : dz - 0.5f;
    float hw = (dw < 1.f) ? 0.5f * dw * dw : dw - 0.5f;
    return (hx + hy) + (hz + hw);
}

// ---- block-level reduce tail shared by all reduce kernels (R2-exact) ----
__device__ __forceinline__ void
block_reduce_store(float s0, float s1, float s2, float sg,
                   float4* __restrict__ partial) {
    #pragma unroll
    for (int off = 32; off > 0; off >>= 1) {
        s0 += __shfl_down(s0, off);
        s1 += __shfl_down(s1, off);
        s2 += __shfl_down(s2, off);
        sg += __shfl_down(sg, off);
    }
    __shared__ float lds[4][4];
    const int wave = threadIdx.x >> 6;
    const int lane = threadIdx.x & 63;
    if (lane == 0) {
        lds[wave][0] = s0; lds[wave][1] = s1;
        lds[wave][2] = s2; lds[wave][3] = sg;
    }
    __syncthreads();
    if (threadIdx.x == 0) {
        float4 r;
        r.x = lds[0][0] + lds[1][0] + lds[2][0] + lds[3][0];
        r.y = lds[0][1] + lds[1][1] + lds[2][1] + lds[3][1];
        r.z = lds[0][2] + lds[1][2] + lds[2][2] + lds[3][2];
        r.w = lds[0][3] + lds[1][3] + lds[2][3] + lds[3][3];
        partial[blockIdx.x] = r;
    }
}

// ---- role-split kernel: geometry blocks [0,GEO_BLOCKS), score after ----
// requires n_g4 == 4*GEO_BLOCKS*THREADS and n_s4 == 4*SCORE_BLOCKS*THREADS
__global__ __launch_bounds__(THREADS) void
loss_reduce_split(const float4* __restrict__ yts,
                  const float4* __restrict__ yps,
                  const float4* __restrict__ ytg,
                  const float4* __restrict__ ypg,
                  float4* __restrict__ partial) {
    float s0 = 0.f, s1 = 0.f, s2 = 0.f, sg = 0.f;

    if (blockIdx.x < GEO_BLOCKS) {
        // ---- geometry: one 4-deep batch (R2-proven codegen) ----
        const int tid = blockIdx.x * THREADS + threadIdx.x;
        const int Tg  = GEO_BLOCKS * THREADS;

        float4 t0 = ytg[tid];
        float4 t1 = ytg[tid + Tg];
        float4 t2 = ytg[tid + 2 * Tg];
        float4 t3 = ytg[tid + 3 * Tg];
        float4 p0 = ypg[tid];
        float4 p1 = ypg[tid + Tg];
        float4 p2 = ypg[tid + 2 * Tg];
        float4 p3 = ypg[tid + 3 * Tg];

        #pragma unroll
        for (int k = 0; k < 4; ++k) {
            float4 t = (k == 0) ? t0 : (k == 1) ? t1 : (k == 2) ? t2 : t3;
            float4 p = (k == 0) ? p0 : (k == 1) ? p1 : (k == 2) ? p2 : p3;
            sg += huber4f(t, p);
        }
    } else {
        // ---- score: 4 float4 per thread, log-heavy, 11% of traffic ----
        const int tid = (blockIdx.x - GEO_BLOCKS) * THREADS + threadIdx.x;
        const int Ts  = SCORE_BLOCKS * THREADS;

        float4 a0 = yts[tid];
        float4 a1 = yts[tid + Ts];
        float4 a2 = yts[tid + 2 * Ts];
        float4 a3 = yts[tid + 3 * Ts];
        float4 b0 = yps[tid];
        float4 b1 = yps[tid + Ts];
        float4 b2 = yps[tid + 2 * Ts];
        float4 b3 = yps[tid + 3 * Ts];

        #pragma unroll
        for (int k = 0; k < 4; ++k) {
            float4 t = (k == 0) ? a0 : (k == 1) ? a1 : (k == 2) ? a2 : a3;
            float4 p = (k == 0) ? b0 : (k == 1) ? b1 : (k == 2) ? b2 : b3;
            s0 += (t.x + t.y) + (t.z + t.w);
            s1 += t.x * __logf(p.x) + t.y * __logf(p.y)
                + t.z * __logf(p.z) + t.w * __logf(p.w);
            s2 += (1.f - t.x) * __logf(1.f - p.x)
                + (1.f - t.y) * __logf(1.f - p.y)
                + (1.f - t.z) * __logf(1.f - p.z)
                + (1.f - t.w) * __logf(1.f - p.w);
        }
    }

    block_reduce_store(s0, s1, s2, sg, partial);
}

// ---- generic fallback: round-2 exact main loop ----
__global__ __launch_bounds__(THREADS) void
loss_reduce(const float4* __restrict__ yts,
            const float4* __restrict__ yps,
            const float4* __restrict__ ytg,
            const float4* __restrict__ ypg,
            float4* __restrict__ partial,
            int n_s4, int n_g4) {
    const int tid = blockIdx.x * THREADS + threadIdx.x;
    const int T   = gridDim.x * THREADS;

    float s0 = 0.f, s1 = 0.f, s2 = 0.f, sg = 0.f;

    for (int i = tid; i < n_s4; i += T) {
        float4 t = yts[i];
        float4 p = yps[i];
        s0 += (t.x + t.y) + (t.z + t.w);
        s1 += t.x * __logf(p.x) + t.y * __logf(p.y)
            + t.z * __logf(p.z) + t.w * __logf(p.w);
        s2 += (1.f - t.x) * __logf(1.f - p.x) + (1.f - t.y) * __logf(1.f - p.y)
            + (1.f - t.z) * __logf(1.f - p.z) + (1.f - t.w) * __logf(1.f - p.w);
    }

    int i = tid;
    for (; i + 3 * T < n_g4; i += 4 * T) {
        float4 t0 = ytg[i];
        float4 t1 = ytg[i + T];
        float4 t2 = ytg[i + 2 * T];
        float4 t3 = ytg[i + 3 * T];
        float4 p0 = ypg[i];
        float4 p1 = ypg[i + T];
        float4 p2 = ypg[i + 2 * T];
        float4 p3 = ypg[i + 3 * T];
        #pragma unroll
        for (int k = 0; k < 4; ++k) {
            float4 t = (k == 0) ? t0 : (k == 1) ? t1 : (k == 2) ? t2 : t3;
            float4 p = (k == 0) ? p0 : (k == 1) ? p1 : (k == 2) ? p2 : p3;
            sg += huber4f(t, p);
        }
    }
    for (; i < n_g4; i += T) {
        sg += huber4f(ytg[i], ypg[i]);
    }

    block_reduce_store(s0, s1, s2, sg, partial);
}

__global__ __launch_bounds__(THREADS) void
loss_finalize(const float4* __restrict__ partial, int nblocks,
              float* __restrict__ out,
              float inv_n_score, float inv_m, float inv_geo_div) {
    float s0 = 0.f, s1 = 0.f, s2 = 0.f, sg = 0.f;
    for (int i = threadIdx.x; i < nblocks; i += THREADS) {
        float4 v = partial[i];
        s0 += v.x; s1 += v.y; s2 += v.z; sg += v.w;
    }
    #pragma unroll
    for (int off = 32; off > 0; off >>= 1) {
        s0 += __shfl_down(s0, off);
        s1 += __shfl_down(s1, off);
        s2 += __shfl_down(s2, off);
        sg += __shfl_down(sg, off);
    }
    __shared__ float lds[4][4];
    const int wave = threadIdx.x >> 6;
    const int lane = threadIdx.x & 63;
    if (lane == 0) {
        lds[wave][0] = s0; lds[wave][1] = s1;
        lds[wave][2] = s2; lds[wave][3] = sg;
    }
    __syncthreads();
    if (threadIdx.x == 0) {
        const float S0 = lds[0][0] + lds[1][0] + lds[2][0] + lds[3][0];
        const float S1 = lds[0][1] + lds[1][1] + lds[2][1] + lds[3][1];
        const float S2 = lds[0][2] + lds[1][2] + lds[2][2] + lds[3][2];
        const float SG = lds[0][3] + lds[1][3] + lds[2][3] + lds[3][3];
        const float beta = 1.f - S0 * inv_n_score;
        const float loss_score = (-beta * S1 - (1.f - beta) * S2) * inv_m;
        const float loss_geo   = SG * inv_geo_div;  // LAMBDA_GEOMETRY = 1
        out[0] = loss_score + loss_geo;
    }
}

extern "C" void kernel_launch(void* const* d_in, const int* in_sizes, int n_in,
                              void* d_out, int out_size, void* d_ws, size_t ws_size,
                              hipStream_t stream) {
    const float4* yts = (const float4*)d_in[0];
    const float4* yps = (const float4*)d_in[1];
    const float4* ytg = (const float4*)d_in[2];
    const float4* ypg = (const float4*)d_in[3];
    float* out = (float*)d_out;
    float4* partial = (float4*)d_ws;

    const int n_score = in_sizes[0];          // m*1*H*W = 2,097,152
    const int n_geo   = in_sizes[2];          // m*8*H*W = 16,777,216
    const int n_s4 = n_score / 4;
    const int n_g4 = n_geo / 4;

    // m=128; n_pix = m*H*W = n_score; divisor = n_c * n_pix = 8 * n_score
    const float inv_n_score = 1.f / (float)n_score;
    const float inv_m       = 1.f / 128.f;
    const float inv_geo_div = 1.f / (8.f * (float)n_score);

    const bool shape_ok =
        (n_g4 == 4 * GEO_BLOCKS * THREADS) &&
        (n_s4 == 4 * SCORE_BLOCKS * THREADS);
    const bool ws_ok = ws_size >= (size_t)TOTAL_BLOCKS * sizeof(float4);

    if (shape_ok && ws_ok) {
        loss_reduce_split<<<TOTAL_BLOCKS, THREADS, 0, stream>>>(
            yts, yps, ytg, ypg, partial);
        loss_finalize<<<1, THREADS, 0, stream>>>(partial, TOTAL_BLOCKS, out,
                                                 inv_n_score, inv_m,
                                                 inv_geo_div);
    } else {
        int blocks = FALLBACK_BLOCKS;
        const size_t need = (size_t)blocks * sizeof(float4);
        if (ws_size < need) blocks = (int)(ws_size / sizeof(float4));
        loss_reduce<<<blocks, THREADS, 0, stream>>>(yts, yps, ytg, ypg,
                                                    partial, n_s4, n_g4);
        loss_finalize<<<1, THREADS, 0, stream>>>(partial, blocks, out,
                                                 inv_n_score, inv_m,
                                                 inv_geo_div);
    }
}

// Round 10
// 31.457 us; speedup vs baseline: 1.1415x; 1.1415x over previous
//
#include <hip/hip_runtime.h>

// Loss = weighted-BCE(score)/m + Huber(geometry)/(8*n_pix), single fused pass.
// beta = 1 - sum(Y_true_score)/N factors out: S0=sum(yt), S1=sum(yt*log(yp)),
// S2=sum((1-yt)*log(1-yp)), SG=sum(huber); finalize combines.
//
// FINAL (round-10): revert to round-6, the best-measured kernel (31.5us).
// Session evidence:
//  - R1/R3/R4: device-scope fence+atomic tails cost ~100us on gfx950
//    (cross-XCD coherence-point serialization). Never fuse that way here.
//  - R6/R7/R8: compiler sinks loads to uses (VGPR pinned ~32); sched_barrier
//    and asm data-fences do not change duration -> NOT latency-bound.
//  - R9: role-split + 2.25x oversubscription null -> NOT imbalance-bound.
//    rocprof cached-replay passes (FETCH ~0) ran at the SAME duration as
//    HBM passes -> bound is the vector-memory request path (~5.1-5.4 TB/s
//    effective for this read-only pattern), not DRAM.
// Floor arithmetic: 151 MB @ 6.29 TB/s copy ceiling = 24us + ~4us second
// launch ≈ 28us best case; this kernel = 31.5us. Roofline reached.

#define THREADS 256
#define NBLOCKS 2048

__device__ __forceinline__ float huber4(float4 t, float4 p) {
    float dx = fabsf(t.x - p.x);
    float dy = fabsf(t.y - p.y);
    float dz = fabsf(t.z - p.z);
    float dw = fabsf(t.w - p.w);
    float hx = (dx < 1.f) ? 0.5f * dx * dx : dx - 0.5f;
    float hy = (dy < 1.f) ? 0.5f * dy * dy : dy - 0.5f;
    float hz = (dz < 1.f) ? 0.5f * dz * dz : dz - 0.5f;
    float hw = (dw < 1.f) ? 0.5f * dw * dw : dw - 0.5f;
    return (hx + hy) + (hz + hw);
}

// ---- block-level reduce tail shared by both reduce kernels (R2-exact) ----
__device__ __forceinline__ void
block_reduce_store(float s0, float s1, float s2, float sg,
                   float4* __restrict__ partial) {
    #pragma unroll
    for (int off = 32; off > 0; off >>= 1) {
        s0 += __shfl_down(s0, off);
        s1 += __shfl_down(s1, off);
        s2 += __shfl_down(s2, off);
        sg += __shfl_down(sg, off);
    }
    __shared__ float lds[4][4];
    const int wave = threadIdx.x >> 6;
    const int lane = threadIdx.x & 63;
    if (lane == 0) {
        lds[wave][0] = s0; lds[wave][1] = s1;
        lds[wave][2] = s2; lds[wave][3] = sg;
    }
    __syncthreads();
    if (threadIdx.x == 0) {
        float4 r;
        r.x = lds[0][0] + lds[1][0] + lds[2][0] + lds[3][0];
        r.y = lds[0][1] + lds[1][1] + lds[2][1] + lds[3][1];
        r.z = lds[0][2] + lds[1][2] + lds[2][2] + lds[3][2];
        r.w = lds[0][3] + lds[1][3] + lds[2][3] + lds[3][3];
        partial[blockIdx.x] = r;
    }
}

// ---- specialized: n_s4 == T, n_g4 == 8*T exactly ----
__global__ __launch_bounds__(THREADS) void
loss_reduce_exact(const float4* __restrict__ yts,
                  const float4* __restrict__ yps,
                  const float4* __restrict__ ytg,
                  const float4* __restrict__ ypg,
                  float4* __restrict__ partial) {
    const int tid = blockIdx.x * THREADS + threadIdx.x;
    const int T   = gridDim.x * THREADS;

    // issue all 18 loads up-front, in consumption order
    float4 st = yts[tid];
    float4 sp = yps[tid];
    float4 t0 = ytg[tid];         float4 p0 = ypg[tid];
    float4 t1 = ytg[tid + T];     float4 p1 = ypg[tid + T];
    float4 t2 = ytg[tid + 2 * T]; float4 p2 = ypg[tid + 2 * T];
    float4 t3 = ytg[tid + 3 * T]; float4 p3 = ypg[tid + 3 * T];
    float4 t4 = ytg[tid + 4 * T]; float4 p4 = ypg[tid + 4 * T];
    float4 t5 = ytg[tid + 5 * T]; float4 p5 = ypg[tid + 5 * T];
    float4 t6 = ytg[tid + 6 * T]; float4 p6 = ypg[tid + 6 * T];
    float4 t7 = ytg[tid + 7 * T]; float4 p7 = ypg[tid + 7 * T];

    // score BCE partials
    float s0 = (st.x + st.y) + (st.z + st.w);
    float s1 = st.x * __logf(sp.x) + st.y * __logf(sp.y)
             + st.z * __logf(sp.z) + st.w * __logf(sp.w);
    float s2 = (1.f - st.x) * __logf(1.f - sp.x)
             + (1.f - st.y) * __logf(1.f - sp.y)
             + (1.f - st.z) * __logf(1.f - sp.z)
             + (1.f - st.w) * __logf(1.f - sp.w);

    // geometry Huber
    float sg = huber4(t0, p0);
    sg += huber4(t1, p1);
    sg += huber4(t2, p2);
    sg += huber4(t3, p3);
    sg += huber4(t4, p4);
    sg += huber4(t5, p5);
    sg += huber4(t6, p6);
    sg += huber4(t7, p7);

    block_reduce_store(s0, s1, s2, sg, partial);
}

// ---- generic fallback: round-2 exact main loop ----
__global__ __launch_bounds__(THREADS) void
loss_reduce(const float4* __restrict__ yts,
            const float4* __restrict__ yps,
            const float4* __restrict__ ytg,
            const float4* __restrict__ ypg,
            float4* __restrict__ partial,
            int n_s4, int n_g4) {
    const int tid = blockIdx.x * THREADS + threadIdx.x;
    const int T   = gridDim.x * THREADS;

    float s0 = 0.f, s1 = 0.f, s2 = 0.f, sg = 0.f;

    for (int i = tid; i < n_s4; i += T) {
        float4 t = yts[i];
        float4 p = yps[i];
        s0 += (t.x + t.y) + (t.z + t.w);
        s1 += t.x * __logf(p.x) + t.y * __logf(p.y)
            + t.z * __logf(p.z) + t.w * __logf(p.w);
        s2 += (1.f - t.x) * __logf(1.f - p.x) + (1.f - t.y) * __logf(1.f - p.y)
            + (1.f - t.z) * __logf(1.f - p.z) + (1.f - t.w) * __logf(1.f - p.w);
    }

    int i = tid;
    for (; i + 3 * T < n_g4; i += 4 * T) {
        float4 t0 = ytg[i];
        float4 t1 = ytg[i + T];
        float4 t2 = ytg[i + 2 * T];
        float4 t3 = ytg[i + 3 * T];
        float4 p0 = ypg[i];
        float4 p1 = ypg[i + T];
        float4 p2 = ypg[i + 2 * T];
        float4 p3 = ypg[i + 3 * T];
        #pragma unroll
        for (int k = 0; k < 4; ++k) {
            float4 t = (k == 0) ? t0 : (k == 1) ? t1 : (k == 2) ? t2 : t3;
            float4 p = (k == 0) ? p0 : (k == 1) ? p1 : (k == 2) ? p2 : p3;
            sg += huber4(t, p);
        }
    }
    for (; i < n_g4; i += T) {
        sg += huber4(ytg[i], ypg[i]);
    }

    block_reduce_store(s0, s1, s2, sg, partial);
}

__global__ __launch_bounds__(THREADS) void
loss_finalize(const float4* __restrict__ partial, int nblocks,
              float* __restrict__ out,
              float inv_n_score, float inv_m, float inv_geo_div) {
    float s0 = 0.f, s1 = 0.f, s2 = 0.f, sg = 0.f;
    for (int i = threadIdx.x; i < nblocks; i += THREADS) {
        float4 v = partial[i];
        s0 += v.x; s1 += v.y; s2 += v.z; sg += v.w;
    }
    #pragma unroll
    for (int off = 32; off > 0; off >>= 1) {
        s0 += __shfl_down(s0, off);
        s1 += __shfl_down(s1, off);
        s2 += __shfl_down(s2, off);
        sg += __shfl_down(sg, off);
    }
    __shared__ float lds[4][4];
    const int wave = threadIdx.x >> 6;
    const int lane = threadIdx.x & 63;
    if (lane == 0) {
        lds[wave][0] = s0; lds[wave][1] = s1;
        lds[wave][2] = s2; lds[wave][3] = sg;
    }
    __syncthreads();
    if (threadIdx.x == 0) {
        const float S0 = lds[0][0] + lds[1][0] + lds[2][0] + lds[3][0];
        const float S1 = lds[0][1] + lds[1][1] + lds[2][1] + lds[3][1];
        const float S2 = lds[0][2] + lds[1][2] + lds[2][2] + lds[3][2];
        const float SG = lds[0][3] + lds[1][3] + lds[2][3] + lds[3][3];
        const float beta = 1.f - S0 * inv_n_score;
        const float loss_score = (-beta * S1 - (1.f - beta) * S2) * inv_m;
        const float loss_geo   = SG * inv_geo_div;  // LAMBDA_GEOMETRY = 1
        out[0] = loss_score + loss_geo;
    }
}

extern "C" void kernel_launch(void* const* d_in, const int* in_sizes, int n_in,
                              void* d_out, int out_size, void* d_ws, size_t ws_size,
                              hipStream_t stream) {
    const float4* yts = (const float4*)d_in[0];
    const float4* yps = (const float4*)d_in[1];
    const float4* ytg = (const float4*)d_in[2];
    const float4* ypg = (const float4*)d_in[3];
    float* out = (float*)d_out;
    float4* partial = (float4*)d_ws;

    const int n_score = in_sizes[0];          // m*1*H*W = 2,097,152
    const int n_geo   = in_sizes[2];          // m*8*H*W = 16,777,216
    const int n_s4 = n_score / 4;
    const int n_g4 = n_geo / 4;

    int blocks = NBLOCKS;
    const size_t need = (size_t)blocks * sizeof(float4);
    if (ws_size < need) blocks = (int)(ws_size / sizeof(float4));  // safety

    const int T = blocks * THREADS;

    // m=128; n_pix = m*H*W = n_score; divisor = n_c * n_pix = 8 * n_score
    const float inv_n_score = 1.f / (float)n_score;
    const float inv_m       = 1.f / 128.f;
    const float inv_geo_div = 1.f / (8.f * (float)n_score);

    if (n_s4 == T && n_g4 == 8 * T) {
        loss_reduce_exact<<<blocks, THREADS, 0, stream>>>(yts, yps, ytg, ypg,
                                                          partial);
    } else {
        loss_reduce<<<blocks, THREADS, 0, stream>>>(yts, yps, ytg, ypg, partial,
                                                    n_s4, n_g4);
    }
    loss_finalize<<<1, THREADS, 0, stream>>>(partial, blocks, out,
                                             inv_n_score, inv_m, inv_geo_div);
}